// Round 3
// baseline (365.047 us; speedup 1.0000x reference)
//
#include <hip/hip_runtime.h>
#include <math.h>

typedef __attribute__((ext_vector_type(8))) _Float16 half8;
typedef __attribute__((ext_vector_type(4))) float float4_t;

#define NB 2048
#define LL 200
#define DD 128
#define AA 64
#define BPB 4            // batches per block (pipelined)
#define NTHR 512
#define NEG_INF_F -4294967295.0f  // rounds to -2^32 in fp32, matches reference

#define WQ_STRIDE 136   // halves: 128 + 8 pad; 272 B row, 16B-aligned chunks

// ws layout (halves):
//   wbc16 [64][136] @ 0      : fp16 (W1b - W1c)^T, row a, padded
//   w1d16 [64][136] @ 8704   : fp16 W1d^T, row a, padded
//   W2T   [64][64]  @ 17408  : fp16 W2 transposed [c][a]
//   qa fp32 @ byte 43008     : [2048][64]  b1 + q@(W1a+W1c)
#define WS_WBC_H  0
#define WS_W1D_H  8704
#define WS_W2T_H  17408
#define WS_QA_OFF 43008

// ---------------- K1: weight transforms + qA ----------------
__global__ __launch_bounds__(256)
void din_prep(const float* __restrict__ query,
              const float* __restrict__ W1,
              const float* __restrict__ b1,
              const float* __restrict__ W2,
              _Float16* __restrict__ ws16,
              float* __restrict__ qa)
{
    const int tid = threadIdx.x;
    const int blk = blockIdx.x;

    if (blk < 128) {
        __shared__ float sW1s[DD * AA];   // W1a + W1c
        __shared__ float sq[16 * DD];
        const int b0 = blk * 16;
        for (int i = tid; i < DD * AA; i += 256)
            sW1s[i] = W1[i] + W1[2 * DD * AA + i];
        for (int i = tid; i < 16 * DD; i += 256)
            sq[i] = query[(size_t)b0 * DD + i];
        __syncthreads();
        const int lane = tid & 63, bb = tid >> 6;
        for (int g = 0; g < 4; ++g) {
            const int bi = bb * 4 + g;
            float acc = b1[lane];
            #pragma unroll 8
            for (int d = 0; d < DD; ++d)
                acc += sq[bi * DD + d] * sW1s[d * AA + lane];
            qa[(size_t)(b0 + bi) * AA + lane] = acc;
        }
    } else if (blk == 128) {
        // wbc16[a][d] = W1b - W1c ; w1d16[a][d] = W1d ; pad cols 128..135 = 0
        for (int i = tid; i < 64 * 17; i += 256) {
            const int a = i / 17, c = i - a * 17;
            half8 hb, hd;
            if (c == 16) {
                #pragma unroll
                for (int j = 0; j < 8; ++j) { hb[j] = (_Float16)0.f; hd[j] = (_Float16)0.f; }
            } else {
                const int d0 = c * 8;
                #pragma unroll
                for (int j = 0; j < 8; ++j) {
                    const int d = d0 + j;
                    hb[j] = (_Float16)(W1[(DD + d) * AA + a] - W1[(2 * DD + d) * AA + a]);
                    hd[j] = (_Float16)(W1[(3 * DD + d) * AA + a]);
                }
            }
            *(half8*)&ws16[WS_WBC_H + a * WQ_STRIDE + c * 8] = hb;
            *(half8*)&ws16[WS_W1D_H + a * WQ_STRIDE + c * 8] = hd;
        }
    } else {
        // W2T[c][a] dense 64x64 fp16
        _Float16* w2t = ws16 + WS_W2T_H;
        const int c = tid >> 2, j0 = (tid & 3) * 16;
        for (int ch = 0; ch < 2; ++ch) {
            half8 v;
            #pragma unroll
            for (int j = 0; j < 8; ++j)
                v[j] = (_Float16)W2[(j0 + ch * 8 + j) * AA + c];
            *(half8*)&w2t[c * AA + j0 + ch * 8] = v;
        }
    }
}

// ---------------- K2: 4 batches per block, T14 batch pipeline ----------------
// R3: double-buffered sKeys; next batch's keys are ISSUED into registers before
// GEMM(b) and written to LDS during PV(b) -> HBM loads stay in flight while the
// block is in its compute phases (the duty-cycle fix R1/R2 showed was missing).
// W1-transform chunks held in persistent registers; per-batch sWq rebuild = VALU only.
__global__ __launch_bounds__(NTHR, 2)
void din_main(const float* __restrict__ keys,
              const int*   __restrict__ keys_length,
              const float* __restrict__ a1p,
              const float* __restrict__ b2,
              const float* __restrict__ a2p,
              const float* __restrict__ W3,
              const _Float16* __restrict__ ws16,
              const float* __restrict__ qa,
              const float* __restrict__ query,
              float* __restrict__ out,
              float* __restrict__ att)
{
    __shared__ __align__(16) _Float16 sKeys[2][LL * DD];     // 102400 B (double buffer)
    __shared__ __align__(16) _Float16 sWq[AA * WQ_STRIDE];   // 17408 B
    __shared__ __align__(16) _Float16 sH1[8 * 16 * 72];      // 18432 B (also PV f32 scratch)
    __shared__ float sQ[2][136];                             // q double buffer, pad zeroed
    __shared__ float sS[224];
    __shared__ float sRed[16];

    const int tid  = threadIdx.x;
    const int lane = tid & 63, wv = tid >> 6;
    const int col  = lane & 15, quad = lane >> 4;
    const int b0   = blockIdx.x * BPB;
    const float pa1 = a1p[0], pa2 = a2p[0];

    const int4 len4 = *(const int4*)&keys_length[b0];
    const int lens[4] = {len4.x, len4.y, len4.z, len4.w};

    // ---- persistent per-thread weight state ----
    half8 hbR[3], hdR[3];            // W1 transform chunks (ci = tid + k*512)
    #pragma unroll
    for (int k = 0; k < 3; ++k) {
        const int ci = tid + k * NTHR;
        if (ci < 64 * 17) {
            hbR[k] = *(const half8*)&ws16[WS_WBC_H + ci * 8];
            hdR[k] = *(const half8*)&ws16[WS_W1D_H + ci * 8];
        }
    }
    const _Float16* w2t = ws16 + WS_W2T_H;
    half8 w2f[2][4];
    #pragma unroll
    for (int ks = 0; ks < 2; ++ks)
        #pragma unroll
        for (int n = 0; n < 4; ++n)
            w2f[ks][n] = *(const half8*)&w2t[(n * 16 + col) * AA + ks * 32 + quad * 8];
    float b2reg[4], w3reg[4], qaC[4];
    #pragma unroll
    for (int n = 0; n < 4; ++n) {
        b2reg[n] = b2[n * 16 + col];
        w3reg[n] = W3[n * 16 + col];
        qaC[n]   = qa[(size_t)b0 * AA + n * 16 + col];
    }

    // ---- prologue: stage batch 0 ----
    float qcur = 0.f;
    if (tid < DD) qcur = query[(size_t)b0 * DD + tid];
    if (tid >= DD && tid < 136) { sQ[0][tid] = 0.f; sQ[1][tid] = 0.f; }
    {
        const int len0  = lens[0];
        const int Lcap0 = len0 ? len0 : LL;
        const float* kbase = keys + (size_t)b0 * LL * DD;
        #pragma unroll
        for (int it = 0; it < 7; ++it) {
            const int i = tid + it * NTHR;
            if (i < Lcap0 * 16) {
                const int l = i >> 4, c8 = i & 15;
                const float* kp = kbase + l * DD + c8 * 8;
                const float4 v0 = *(const float4*)kp;
                const float4 v1 = *(const float4*)(kp + 4);
                half8 h;
                h[0] = (_Float16)v0.x; h[1] = (_Float16)v0.y;
                h[2] = (_Float16)v0.z; h[3] = (_Float16)v0.w;
                h[4] = (_Float16)v1.x; h[5] = (_Float16)v1.y;
                h[6] = (_Float16)v1.z; h[7] = (_Float16)v1.w;
                *(half8*)&sKeys[0][l * DD + ((c8 ^ (l & 7)) << 3)] = h;
            }
        }
    }
    if (tid < DD) sQ[0][tid] = qcur;
    for (int i = tid; i < 224; i += NTHR) sS[i] = NEG_INF_F;
    __syncthreads();
    // build sWq(0) from register-held weights (VALU only)
    #pragma unroll
    for (int k = 0; k < 3; ++k) {
        const int ci = tid + k * NTHR;
        if (ci < 64 * 17) {
            const int c = ci % 17, d0 = c * 8;
            half8 r;
            #pragma unroll
            for (int j = 0; j < 8; ++j)
                r[j] = (_Float16)((float)hbR[k][j] + sQ[0][d0 + j] * (float)hdR[k][j]);
            *(half8*)&sWq[ci * 8] = r;
        }
    }
    __syncthreads();

    float4 kr[7][2];
    float qnext = 0.f;
    float qaN[4] = {0.f, 0.f, 0.f, 0.f};
    int cur = 0;

    for (int bi = 0; bi < BPB; ++bi) {
        const int b      = b0 + bi;
        const int len    = lens[bi];
        const int Lcap   = len ? len : LL;
        const int ntiles = (len + 15) >> 4;
        const int nxt    = cur ^ 1;
        const bool pf    = (bi + 1 < BPB);

        // ---- A: issue prefetch for batch b+1 (drains under GEMM+softmax) ----
        int LcapN = 0;
        if (pf) {
            const int lenN = lens[bi + 1];
            LcapN = lenN ? lenN : LL;
            const float* kbase = keys + (size_t)(b + 1) * LL * DD;
            #pragma unroll
            for (int it = 0; it < 7; ++it) {
                const int i = tid + it * NTHR;
                if (i < LcapN * 16) {
                    const int l = i >> 4, c8 = i & 15;
                    const float* kp = kbase + l * DD + c8 * 8;
                    kr[it][0] = *(const float4*)kp;
                    kr[it][1] = *(const float4*)(kp + 4);
                }
            }
            if (tid < DD) qnext = query[(size_t)(b + 1) * DD + tid];
            #pragma unroll
            for (int n = 0; n < 4; ++n)
                qaN[n] = qa[(size_t)(b + 1) * AA + n * 16 + col];
        }

        // ---- B: GEMM(b), tiles strided over 8 waves ----
        _Float16* const myH = &sH1[wv * 16 * 72];
        for (int t = wv; t < ntiles; t += 8) {
            const int l0 = t * 16;
            const int lr = (l0 + col < LL) ? (l0 + col) : (LL - 1);  // clamp; masked later

            float4_t C[4] = {{0,0,0,0},{0,0,0,0},{0,0,0,0},{0,0,0,0}};
            #pragma unroll
            for (int ks = 0; ks < 4; ++ks) {
                const int swz = ((ks * 4 + quad) ^ (lr & 7)) << 3;
                const half8 af = *(const half8*)&sKeys[cur][lr * DD + swz];
                const int ko = ks * 32 + quad * 8;
                #pragma unroll
                for (int n = 0; n < 4; ++n) {
                    const half8 bf = *(const half8*)&sWq[(n * 16 + col) * WQ_STRIDE + ko];
                    C[n] = __builtin_amdgcn_mfma_f32_16x16x32_f16(af, bf, C[n], 0, 0, 0);
                }
            }
            #pragma unroll
            for (int n = 0; n < 4; ++n)
                #pragma unroll
                for (int r = 0; r < 4; ++r) {
                    float v = C[n][r] + qaC[n];
                    v = v >= 0.f ? v : pa1 * v;
                    myH[(quad * 4 + r) * 72 + n * 16 + col] = (_Float16)v;
                }
            float4_t D[4] = {{0,0,0,0},{0,0,0,0},{0,0,0,0},{0,0,0,0}};
            #pragma unroll
            for (int ks = 0; ks < 2; ++ks) {
                const half8 af = *(const half8*)&myH[col * 72 + ks * 32 + quad * 8];
                #pragma unroll
                for (int n = 0; n < 4; ++n)
                    D[n] = __builtin_amdgcn_mfma_f32_16x16x32_f16(af, w2f[ks][n], D[n], 0, 0, 0);
            }
            float pr[4] = {0.f, 0.f, 0.f, 0.f};
            #pragma unroll
            for (int n = 0; n < 4; ++n)
                #pragma unroll
                for (int r = 0; r < 4; ++r) {
                    float v = D[n][r] + b2reg[n];
                    v = v >= 0.f ? v : pa2 * v;
                    pr[r] += v * w3reg[n];
                }
            #pragma unroll
            for (int r = 0; r < 4; ++r) {
                float pv = pr[r];
                pv += __shfl_xor(pv, 1);
                pv += __shfl_xor(pv, 2);
                pv += __shfl_xor(pv, 4);
                pv += __shfl_xor(pv, 8);
                const int l = l0 + quad * 4 + r;
                if (col == 0 && l < len) sS[l] = pv;
            }
        }
        __syncthreads();

        // ---- C: masked softmax over sS[0..199] ----
        float m = (tid < LL) ? sS[tid] : -INFINITY;
        #pragma unroll
        for (int o = 1; o < 64; o <<= 1) m = fmaxf(m, __shfl_xor(m, o));
        if (lane == 0) sRed[wv] = m;
        __syncthreads();
        float M = sRed[0];
        #pragma unroll
        for (int i = 1; i < 8; ++i) M = fmaxf(M, sRed[i]);
        float e = (tid < LL) ? expf(sS[tid] - M) : 0.f;
        float s = e;
        #pragma unroll
        for (int o = 1; o < 64; o <<= 1) s += __shfl_xor(s, o);
        if (lane == 0) sRed[8 + wv] = s;
        __syncthreads();
        float S = sRed[8];
        #pragma unroll
        for (int i = 9; i < 16; ++i) S += sRed[i];
        const float inv = 1.f / S;
        if (tid < LL) {
            const float v = e * inv;
            sS[tid] = v;
            att[(size_t)b * LL + tid] = v;
        }
        __syncthreads();

        // ---- D: PV partial from sKeys[cur] + write prefetched batch into sKeys[nxt] ----
        if (pf && tid < DD) sQ[nxt][tid] = qnext;
        {
            const int c8 = tid & 15, ph = tid >> 4;
            float acc[8];
            #pragma unroll
            for (int j = 0; j < 8; ++j) acc[j] = 0.f;
            for (int l = ph; l < Lcap; l += 32) {
                const float w = sS[l];
                const half8 kv = *(const half8*)&sKeys[cur][l * DD + ((c8 ^ (l & 7)) << 3)];
                #pragma unroll
                for (int j = 0; j < 8; ++j) acc[j] += w * (float)kv[j];
            }
            float* const scratch = (float*)sH1;   // sH1 dead until next GEMM; 16384 B <= 18432 B
            #pragma unroll
            for (int j = 0; j < 8; ++j) scratch[tid * 8 + j] = acc[j];
        }
        if (pf) {
            #pragma unroll
            for (int it = 0; it < 7; ++it) {
                const int i = tid + it * NTHR;
                if (i < LcapN * 16) {
                    const int l = i >> 4, c8 = i & 15;
                    const float4 v0 = kr[it][0], v1 = kr[it][1];
                    half8 h;
                    h[0] = (_Float16)v0.x; h[1] = (_Float16)v0.y;
                    h[2] = (_Float16)v0.z; h[3] = (_Float16)v0.w;
                    h[4] = (_Float16)v1.x; h[5] = (_Float16)v1.y;
                    h[6] = (_Float16)v1.z; h[7] = (_Float16)v1.w;
                    *(half8*)&sKeys[nxt][l * DD + ((c8 ^ (l & 7)) << 3)] = h;
                }
            }
        }
        __syncthreads();

        // ---- E: PV reduce -> out; rebuild sWq for b+1; reset sS ----
        {
            const float* scratch = (const float*)sH1;
            if (tid < DD) {
                const int c8o = tid >> 3, j = tid & 7;
                float r = 0.f;
                #pragma unroll
                for (int p = 0; p < 32; ++p) r += scratch[(p * 16 + c8o) * 8 + j];
                out[(size_t)b * DD + tid] = r;
            }
        }
        if (pf) {
            #pragma unroll
            for (int k = 0; k < 3; ++k) {
                const int ci = tid + k * NTHR;
                if (ci < 64 * 17) {
                    const int c = ci % 17, d0 = c * 8;
                    half8 r;
                    #pragma unroll
                    for (int j = 0; j < 8; ++j)
                        r[j] = (_Float16)((float)hbR[k][j] + sQ[nxt][d0 + j] * (float)hdR[k][j]);
                    *(half8*)&sWq[ci * 8] = r;
                }
            }
            #pragma unroll
            for (int n = 0; n < 4; ++n) qaC[n] = qaN[n];
        }
        for (int i = tid; i < 224; i += NTHR) sS[i] = NEG_INF_F;
        __syncthreads();
        cur = nxt;
    }
}

extern "C" void kernel_launch(void* const* d_in, const int* in_sizes, int n_in,
                              void* d_out, int out_size, void* d_ws, size_t ws_size,
                              hipStream_t stream) {
    (void)in_sizes; (void)n_in; (void)ws_size; (void)out_size;
    const float* query = (const float*)d_in[0];
    const float* keys  = (const float*)d_in[1];
    const int*   klen  = (const int*)d_in[2];
    const float* W1    = (const float*)d_in[3];
    const float* b1    = (const float*)d_in[4];
    const float* a1    = (const float*)d_in[5];
    const float* W2    = (const float*)d_in[6];
    const float* b2    = (const float*)d_in[7];
    const float* a2    = (const float*)d_in[8];
    const float* W3    = (const float*)d_in[9];
    // d_in[10] = b3: irrelevant to both outputs (softmax shift invariance)

    _Float16* ws16 = (_Float16*)d_ws;
    float*    qawk = (float*)((char*)d_ws + WS_QA_OFF);

    float* out = (float*)d_out;                  // (B, D) fp32
    float* att = out + (size_t)NB * DD;          // (B, L) fp32

    hipLaunchKernelGGL(din_prep, dim3(130), dim3(256), 0, stream,
                       query, W1, b1, W2, ws16, qawk);
    hipLaunchKernelGGL(din_main, dim3(NB / BPB), dim3(NTHR), 0, stream,
                       keys, klen, a1, b2, a2, W3, ws16, qawk, query, out, att);
}